// Round 16
// baseline (280.411 us; speedup 1.0000x reference)
//
#include <hip/hip_runtime.h>
#include <stdint.h>

#define MT   30      // top-M candidates
#define KNB  20      // K+1 neighbors
#define DD   512     // descriptor dim
#define SROW 68      // staged row stride (floats): 272B, 16B-aligned
#define MWS  32      // padded MwS row stride (floats)

// ===== Fused kernel: decisions (round-3 chains verbatim) + x_dba tail =====
// r11 structure (256 thr, (256,6), fused tail) + sim retiled to 3x3 on ONE
// wave (55 tiles, lanes 0-54) per r13's hazard-fixed combine. Do NOT tighten
// the occupancy cap: (256,8) pinned VGPR=32 and spilled 2.7 GB (r14); (512,4)
// likewise (r4). The f64 phases need ~80 live VGPRs.
extern "C" __global__ void __launch_bounds__(256, 6)
mdesc_fused(const float* __restrict__ X, const float* __restrict__ Q,
            const int* __restrict__ ranks, float* __restrict__ out, int B)
{
    // arrA: XtS (stage phase) aliased with {MwS, scoreS, orderS} (post-stage)
    __shared__ alignas(16) char arrA[MT * SROW * 4];   // 8160 B
    __shared__ alignas(16) float QS[DD];
    __shared__ double simS[MT][MT + 1];
    __shared__ double qdotPart[MT][8];
    __shared__ double qdotS[MT];
    __shared__ int    rtS[MT];

    float  (*XtS)[SROW] = (float(*)[SROW])arrA;
    float  (*MwS)[MWS]  = (float(*)[MWS])arrA;         // 30x32 f32 = 3840 B
    double *scoreS      = (double*)(arrA + 3840);      // 240 B
    int    *orderS      = (int*)(arrA + 4080);         // 120 B

    const int b = blockIdx.x;
    const int tid = threadIdx.x;

    if (tid < MT) rtS[tid] = ranks[(size_t)tid * B + b];
    __syncthreads();

    // wave 0: 55 sim tiles (3x3 over upper-tri of 10x10 supertiles)
    const bool isSim = (tid < 55);
    int i0 = 0, j0 = 0;
    if (isSim) {
        int I = 0, rem = tid;
        while (rem >= 10 - I) { rem -= 10 - I; ++I; }
        i0 = 3 * I; j0 = 3 * (I + rem);
    }
    // waves 2-3: qdot lanes (verbatim r11 mapping)
    const bool isQ = (tid >= 128 && tid < 248);
    const int qm = (tid - 128) >> 2;   // 0..29
    const int qs = (tid - 128) & 3;    // 0..3

    double a00 = 0.0, a01 = 0.0, a02 = 0.0;
    double a10 = 0.0, a11 = 0.0, a12 = 0.0;
    double a20 = 0.0, a21 = 0.0, a22 = 0.0;

    for (int st = 0; st < 8; ++st) {
        // ---- stage 64 d-values of all 30 rows (coalesced float4) ----
        for (int i = tid; i < MT * 16; i += 256) {
            int row = i >> 4;
            int k = i & 15;
            float4 v = *(const float4*)(X + (size_t)rtS[row] * DD + st * 64 + (k << 2));
            *(float4*)(&XtS[row][k << 2]) = v;
        }
        if (st == 0 && tid < 128) {
            float4 v = *(const float4*)(Q + (size_t)b * DD + (tid << 2));
            *(float4*)(&QS[tid << 2]) = v;
        }
        __syncthreads();

        // ---- sim: 3x3 tile, per-entry ascending-d f64 chains (verbatim round 3) ----
        if (isSim) {
            const float* R0 = &XtS[i0][0];
            const float* R1 = &XtS[i0 + 1][0];
            const float* R2 = &XtS[i0 + 2][0];
            const float* C0 = &XtS[j0][0];
            const float* C1 = &XtS[j0 + 1][0];
            const float* C2 = &XtS[j0 + 2][0];
            for (int k = 0; k < 16; ++k) {
                float4 va0 = *(const float4*)(R0 + (k << 2));
                float4 va1 = *(const float4*)(R1 + (k << 2));
                float4 va2 = *(const float4*)(R2 + (k << 2));
                float4 vb0 = *(const float4*)(C0 + (k << 2));
                float4 vb1 = *(const float4*)(C1 + (k << 2));
                float4 vb2 = *(const float4*)(C2 + (k << 2));
                const float* A0 = (const float*)&va0;
                const float* A1 = (const float*)&va1;
                const float* A2 = (const float*)&va2;
                const float* B0 = (const float*)&vb0;
                const float* B1 = (const float*)&vb1;
                const float* B2 = (const float*)&vb2;
                #pragma unroll
                for (int c = 0; c < 4; ++c) {
                    double x0 = (double)A0[c], x1 = (double)A1[c], x2 = (double)A2[c];
                    double y0 = (double)B0[c], y1 = (double)B1[c], y2 = (double)B2[c];
                    a00 = fma(x0, y0, a00); a01 = fma(x0, y1, a01); a02 = fma(x0, y2, a02);
                    a10 = fma(x1, y0, a10); a11 = fma(x1, y1, a11); a12 = fma(x1, y2, a12);
                    a20 = fma(x2, y0, a20); a21 = fma(x2, y1, a21); a22 = fma(x2, y2, a22);
                }
            }
            if (st == 3) {   // end of half 0: stash in owned simS slots (disjoint per tile)
                simS[i0    ][j0] = a00; simS[i0    ][j0 + 1] = a01; simS[i0    ][j0 + 2] = a02;
                simS[i0 + 1][j0] = a10; simS[i0 + 1][j0 + 1] = a11; simS[i0 + 1][j0 + 2] = a12;
                simS[i0 + 2][j0] = a20; simS[i0 + 2][j0 + 1] = a21; simS[i0 + 2][j0 + 2] = a22;
                a00 = a01 = a02 = a10 = a11 = a12 = a20 = a21 = a22 = 0.0;
            }
            if (st == 7) {
                // HAZARD FIX (r13): read ALL stash values BEFORE any write
                // (diagonal supertiles' mirror slots alias other entries' stash).
                double h00v = simS[i0    ][j0]; double h01v = simS[i0    ][j0 + 1]; double h02v = simS[i0    ][j0 + 2];
                double h10v = simS[i0 + 1][j0]; double h11v = simS[i0 + 1][j0 + 1]; double h12v = simS[i0 + 1][j0 + 2];
                double h20v = simS[i0 + 2][j0]; double h21v = simS[i0 + 2][j0 + 1]; double h22v = simS[i0 + 2][j0 + 2];
                double s00 = h00v + a00, s01 = h01v + a01, s02 = h02v + a02;
                double s10 = h10v + a10, s11 = h11v + a11, s12 = h12v + a12;
                double s20 = h20v + a20, s21 = h21v + a21, s22 = h22v + a22;
                simS[i0    ][j0] = s00; simS[j0    ][i0] = s00;
                simS[i0    ][j0 + 1] = s01; simS[j0 + 1][i0] = s01;
                simS[i0    ][j0 + 2] = s02; simS[j0 + 2][i0] = s02;
                simS[i0 + 1][j0] = s10; simS[j0    ][i0 + 1] = s10;
                simS[i0 + 1][j0 + 1] = s11; simS[j0 + 1][i0 + 1] = s11;
                simS[i0 + 1][j0 + 2] = s12; simS[j0 + 2][i0 + 1] = s12;
                simS[i0 + 2][j0] = s20; simS[j0    ][i0 + 2] = s20;
                simS[i0 + 2][j0 + 1] = s21; simS[j0 + 1][i0 + 2] = s21;
                simS[i0 + 2][j0 + 2] = s22; simS[j0 + 2][i0 + 2] = s22;
            }
        }
        // ---- qdot: lane (qm,qs) handles s = st when (st&3)==qs; 64-float chain ----
        if (isQ && (st & 3) == qs) {
            double acc = 0.0;
            const float* xr = &XtS[qm][0];
            for (int k = 0; k < 16; ++k) {
                float4 q4 = *(const float4*)(&QS[(st * 16 + k) << 2]);
                float4 x4 = *(const float4*)(xr + (k << 2));
                const float* qq = (const float*)&q4;
                const float* xx = (const float*)&x4;
                #pragma unroll
                for (int c = 0; c < 4; ++c)
                    acc = fma((double)qq[c], (double)xx[c], acc);
            }
            qdotPart[qm][st] = acc;
        }
        __syncthreads();
    }

    // ---- XtS dead; zero aliased MwS (padded 30x32) ----
    for (int i = tid; i < MT * MWS; i += 256) (&MwS[0][0])[i] = 0.0f;
    __syncthreads();

    // ---- wave-0 serial: qdot sum, top-20 selection, score, rank, head outputs ----
    const size_t sec = (size_t)B * MT;
    if (tid < MT) {
        {
            double acc = 0.0;
            #pragma unroll
            for (int s = 0; s < 8; ++s) acc += qdotPart[tid][s];
            qdotS[tid] = acc;
        }
        const int m = tid;
        unsigned used = 0;
        double Wsum = 0.0, sAcc = 0.0;
        for (int k = 0; k < KNB; ++k) {
            double best = -1.0e300; int bj = 0;
            for (int j = 0; j < MT; ++j) {
                if (used & (1u << j)) continue;
                double v = simS[m][j];
                if (v > best) { best = v; bj = j; }
            }
            used |= (1u << bj);
            double w = (k == 0) ? 1.0 : best * 0.15;
            Wsum += w;
            sAcc = fma(w, qdotS[bj], sAcc);
            MwS[m][bj] = (float)w;
        }
        scoreS[m] = sAcc / Wsum;
        float inv = (float)(1.0 / Wsum);
        for (int j = 0; j < MT; ++j)
            if (used & (1u << j)) MwS[m][j] *= inv;
        // stable rank (desc, ties -> lowest index)
        double mysc = scoreS[tid];
        int pos = 0;
        for (int j = 0; j < MT; ++j) {
            double v = scoreS[j];
            if (v > mysc || (v == mysc && j < tid)) ++pos;
        }
        orderS[pos] = tid;
        // head outputs
        int r = tid;
        int src = orderS[r];
        out[(size_t)b * MT + r]            = (float)rtS[src];
        out[sec + (size_t)b * MT + tid]    = (float)scoreS[tid];
        out[2 * sec + (size_t)b * MT + r]  = (float)src;
    }
    __syncthreads();

    // ---- fused x_dba tail: X from global (L2-hot), w as b64 broadcasts ----
    {
        const int sub = tid >> 7;          // 0..1 (15-row group)
        const int c   = tid & 127;         // float4 chunk
        const int r0  = sub * 15;
        float4 acc[15];
        #pragma unroll
        for (int r = 0; r < 15; ++r) acc[r] = make_float4(0.f, 0.f, 0.f, 0.f);

        for (int jg = 0; jg < 15; ++jg) {
            const int ja = 2 * jg, jb = ja + 1;
            float4 xv0 = *(const float4*)(X + (size_t)rtS[ja] * DD + (c << 2));
            float4 xv1 = *(const float4*)(X + (size_t)rtS[jb] * DD + (c << 2));
            #pragma unroll
            for (int r = 0; r < 15; ++r) {
                float2 wv = *(const float2*)&MwS[r0 + r][ja];   // 8B-aligned broadcast
                acc[r].x = fmaf(wv.x, xv0.x, acc[r].x);
                acc[r].x = fmaf(wv.y, xv1.x, acc[r].x);
                acc[r].y = fmaf(wv.x, xv0.y, acc[r].y);
                acc[r].y = fmaf(wv.y, xv1.y, acc[r].y);
                acc[r].z = fmaf(wv.x, xv0.z, acc[r].z);
                acc[r].z = fmaf(wv.y, xv1.z, acc[r].z);
                acc[r].w = fmaf(wv.x, xv0.w, acc[r].w);
                acc[r].w = fmaf(wv.y, xv1.w, acc[r].w);
            }
        }

        const size_t xbase = 3 * sec;
        #pragma unroll
        for (int r = 0; r < 15; ++r) {
            *(float4*)(out + xbase + ((size_t)b * MT + (r0 + r)) * DD + (c << 2)) = acc[r];
        }
    }
}

extern "C" void kernel_launch(void* const* d_in, const int* in_sizes, int n_in,
                              void* d_out, int out_size, void* d_ws, size_t ws_size,
                              hipStream_t stream)
{
    const float* X = (const float*)d_in[0];
    const float* Q = (const float*)d_in[1];
    const int* ranks = (const int*)d_in[2];
    const int B = in_sizes[1] / DD;   // 4096
    mdesc_fused<<<dim3(B), dim3(256), 0, stream>>>(X, Q, ranks, (float*)d_out, B);
}

// Round 17
// 247.332 us; speedup vs baseline: 1.1337x; 1.1337x over previous
//
#include <hip/hip_runtime.h>
#include <stdint.h>

#define MT   30      // top-M candidates
#define KNB  20      // K+1 neighbors
#define DD   512     // descriptor dim
#define SROW 68      // staged row stride (floats): 272B, 16B-aligned
#define MWS  32      // padded MwS row stride (floats)

// ===== Fused kernel: decisions (round-3 chains verbatim) + x_dba tail =====
// ROUND-11 OPTIMUM (245.1 us measured). Locked-in decisions:
//  - 2x2 sim tiles on waves 0-1, qdot on waves 2-3 (concentrating sim on
//    fewer waves regressed: r13 289, r16 280).
//  - (256,6): do NOT tighten — (256,8) pinned VGPR=32, spilled 2.7 GB
//    (r14, 889 us); (512,4) likewise (r4). f64 phases need ~85 live VGPRs.
//  - Decision chains (sim/qdot/selection/rank) are BITWISE round-3: any
//    reorder re-rolls near-tie rank flips vs the f64 numpy reference.
extern "C" __global__ void __launch_bounds__(256, 6)
mdesc_fused(const float* __restrict__ X, const float* __restrict__ Q,
            const int* __restrict__ ranks, float* __restrict__ out, int B)
{
    // arrA: XtS (stage phase) aliased with {MwS, scoreS, orderS} (post-stage)
    __shared__ alignas(16) char arrA[MT * SROW * 4];   // 8160 B
    __shared__ alignas(16) float QS[DD];
    __shared__ double simS[MT][MT + 1];
    __shared__ double qdotPart[MT][8];
    __shared__ double qdotS[MT];
    __shared__ int    rtS[MT];

    float  (*XtS)[SROW] = (float(*)[SROW])arrA;
    float  (*MwS)[MWS]  = (float(*)[MWS])arrA;         // 30x32 f32 = 3840 B
    double *scoreS      = (double*)(arrA + 3840);      // 240 B
    int    *orderS      = (int*)(arrA + 4080);         // 120 B

    const int b = blockIdx.x;
    const int tid = threadIdx.x;

    if (tid < MT) rtS[tid] = ranks[(size_t)tid * B + b];
    __syncthreads();

    // roles: waves 0-1 = sim tiles (120 lanes), waves 2-3 = qdot (120 lanes)
    const bool isSim = (tid < 120);
    const bool isQ   = (tid >= 128 && tid < 248);
    int i0 = 0, i1 = 0, j0 = 0, j1 = 0;
    if (isSim) {
        int I = 0, rem = tid;
        while (rem >= 15 - I) { rem -= 15 - I; ++I; }
        int J = I + rem;
        i0 = 2 * I; i1 = i0 + 1; j0 = 2 * J; j1 = j0 + 1;
    }
    const int qm = (tid - 128) >> 2;   // 0..29
    const int qs = (tid - 128) & 3;    // 0..3

    double a00 = 0.0, a01 = 0.0, a10 = 0.0, a11 = 0.0;

    for (int st = 0; st < 8; ++st) {
        // ---- stage 64 d-values of all 30 rows (coalesced float4) ----
        for (int i = tid; i < MT * 16; i += 256) {
            int row = i >> 4;
            int k = i & 15;
            float4 v = *(const float4*)(X + (size_t)rtS[row] * DD + st * 64 + (k << 2));
            *(float4*)(&XtS[row][k << 2]) = v;
        }
        if (st == 0 && tid < 128) {
            float4 v = *(const float4*)(Q + (size_t)b * DD + (tid << 2));
            *(float4*)(&QS[tid << 2]) = v;
        }
        __syncthreads();

        // ---- sim: continuous ascending-d f64 chains (verbatim round 3 per entry) ----
        if (isSim) {
            const float* R0 = &XtS[i0][0];
            const float* R1 = &XtS[i1][0];
            const float* C0 = &XtS[j0][0];
            const float* C1 = &XtS[j1][0];
            for (int k = 0; k < 16; ++k) {
                float4 va0 = *(const float4*)(R0 + (k << 2));
                float4 va1 = *(const float4*)(R1 + (k << 2));
                float4 vb0 = *(const float4*)(C0 + (k << 2));
                float4 vb1 = *(const float4*)(C1 + (k << 2));
                const float* A0 = (const float*)&va0;
                const float* A1 = (const float*)&va1;
                const float* B0 = (const float*)&vb0;
                const float* B1 = (const float*)&vb1;
                #pragma unroll
                for (int c = 0; c < 4; ++c) {
                    double x0 = (double)A0[c], x1 = (double)A1[c];
                    double y0 = (double)B0[c], y1 = (double)B1[c];
                    a00 = fma(x0, y0, a00);
                    a01 = fma(x0, y1, a01);
                    a10 = fma(x1, y0, a10);
                    a11 = fma(x1, y1, a11);
                }
            }
            if (st == 3) {              // end of half 0: stash in own simS slots
                simS[i0][j0] = a00; simS[i0][j1] = a01;
                simS[i1][j0] = a10; simS[i1][j1] = a11;
                a00 = a01 = a10 = a11 = 0.0;
            }
            if (st == 7) {              // combine h0 + h1, exactly as round 3
                double s00 = simS[i0][j0] + a00;
                double s01 = simS[i0][j1] + a01;
                double s10 = simS[i1][j0] + a10;
                double s11 = simS[i1][j1] + a11;
                simS[i0][j0] = s00; simS[j0][i0] = s00;
                simS[i0][j1] = s01; simS[j1][i0] = s01;
                simS[i1][j0] = s10; simS[j0][i1] = s10;
                simS[i1][j1] = s11; simS[j1][i1] = s11;
            }
        }
        // ---- qdot: lane (qm,qs) handles s = st when (st&3)==qs; 64-float chain ----
        if (isQ && (st & 3) == qs) {
            double acc = 0.0;
            const float* xr = &XtS[qm][0];
            for (int k = 0; k < 16; ++k) {
                float4 q4 = *(const float4*)(&QS[(st * 16 + k) << 2]);
                float4 x4 = *(const float4*)(xr + (k << 2));
                const float* qq = (const float*)&q4;
                const float* xx = (const float*)&x4;
                #pragma unroll
                for (int c = 0; c < 4; ++c)
                    acc = fma((double)qq[c], (double)xx[c], acc);
            }
            qdotPart[qm][st] = acc;
        }
        __syncthreads();
    }

    // ---- XtS dead; zero aliased MwS (padded 30x32) ----
    for (int i = tid; i < MT * MWS; i += 256) (&MwS[0][0])[i] = 0.0f;
    __syncthreads();

    // ---- wave-0 serial: qdot sum, top-20 selection, score, rank, head outputs ----
    const size_t sec = (size_t)B * MT;
    if (tid < MT) {
        {
            double acc = 0.0;
            #pragma unroll
            for (int s = 0; s < 8; ++s) acc += qdotPart[tid][s];
            qdotS[tid] = acc;
        }
        const int m = tid;
        unsigned used = 0;
        double Wsum = 0.0, sAcc = 0.0;
        for (int k = 0; k < KNB; ++k) {
            double best = -1.0e300; int bj = 0;
            for (int j = 0; j < MT; ++j) {
                if (used & (1u << j)) continue;
                double v = simS[m][j];
                if (v > best) { best = v; bj = j; }
            }
            used |= (1u << bj);
            double w = (k == 0) ? 1.0 : best * 0.15;
            Wsum += w;
            sAcc = fma(w, qdotS[bj], sAcc);
            MwS[m][bj] = (float)w;
        }
        scoreS[m] = sAcc / Wsum;
        float inv = (float)(1.0 / Wsum);
        for (int j = 0; j < MT; ++j)
            if (used & (1u << j)) MwS[m][j] *= inv;
        // stable rank (desc, ties -> lowest index)
        double mysc = scoreS[tid];
        int pos = 0;
        for (int j = 0; j < MT; ++j) {
            double v = scoreS[j];
            if (v > mysc || (v == mysc && j < tid)) ++pos;
        }
        orderS[pos] = tid;
        // head outputs
        int r = tid;
        int src = orderS[r];
        out[(size_t)b * MT + r]            = (float)rtS[src];
        out[sec + (size_t)b * MT + tid]    = (float)scoreS[tid];
        out[2 * sec + (size_t)b * MT + r]  = (float)src;
    }
    __syncthreads();

    // ---- fused x_dba tail: X from global (L2-hot), w as b64 broadcasts ----
    {
        const int sub = tid >> 7;          // 0..1 (15-row group)
        const int c   = tid & 127;         // float4 chunk
        const int r0  = sub * 15;
        float4 acc[15];
        #pragma unroll
        for (int r = 0; r < 15; ++r) acc[r] = make_float4(0.f, 0.f, 0.f, 0.f);

        for (int jg = 0; jg < 15; ++jg) {
            const int ja = 2 * jg, jb = ja + 1;
            float4 xv0 = *(const float4*)(X + (size_t)rtS[ja] * DD + (c << 2));
            float4 xv1 = *(const float4*)(X + (size_t)rtS[jb] * DD + (c << 2));
            #pragma unroll
            for (int r = 0; r < 15; ++r) {
                float2 wv = *(const float2*)&MwS[r0 + r][ja];   // 8B-aligned broadcast
                acc[r].x = fmaf(wv.x, xv0.x, acc[r].x);
                acc[r].x = fmaf(wv.y, xv1.x, acc[r].x);
                acc[r].y = fmaf(wv.x, xv0.y, acc[r].y);
                acc[r].y = fmaf(wv.y, xv1.y, acc[r].y);
                acc[r].z = fmaf(wv.x, xv0.z, acc[r].z);
                acc[r].z = fmaf(wv.y, xv1.z, acc[r].z);
                acc[r].w = fmaf(wv.x, xv0.w, acc[r].w);
                acc[r].w = fmaf(wv.y, xv1.w, acc[r].w);
            }
        }

        const size_t xbase = 3 * sec;
        #pragma unroll
        for (int r = 0; r < 15; ++r) {
            *(float4*)(out + xbase + ((size_t)b * MT + (r0 + r)) * DD + (c << 2)) = acc[r];
        }
    }
}

extern "C" void kernel_launch(void* const* d_in, const int* in_sizes, int n_in,
                              void* d_out, int out_size, void* d_ws, size_t ws_size,
                              hipStream_t stream)
{
    const float* X = (const float*)d_in[0];
    const float* Q = (const float*)d_in[1];
    const int* ranks = (const int*)d_in[2];
    const int B = in_sizes[1] / DD;   // 4096
    mdesc_fused<<<dim3(B), dim3(256), 0, stream>>>(X, Q, ranks, (float*)d_out, B);
}